// Round 12
// baseline (826.425 us; speedup 1.0000x reference)
//
#include <hip/hip_runtime.h>
#include <cstdint>

typedef _Float16 f16;
typedef _Float16 f16x4v __attribute__((ext_vector_type(4)));
typedef _Float16 f16x8 __attribute__((ext_vector_type(8)));
typedef float f32x4 __attribute__((ext_vector_type(4)));

#define DEV static __device__ __forceinline__

// async global->LDS, 16B per lane; LDS dest = wave-uniform base + lane*16
#define GLDS16(gp, lp) __builtin_amdgcn_global_load_lds( \
    (const __attribute__((address_space(1))) void*)(gp), \
    (__attribute__((address_space(3))) void*)(lp), 16, 0, 0)

DEV float sigf(float x) { return 1.0f / (1.0f + __expf(-x)); }
DEV float tanh2(float x) {
  float e = __expf(-2.0f * fabsf(x));
  float t = (1.0f - e) / (1.0f + e);
  return x >= 0.0f ? t : -t;
}

// ---------------- merged fp32 -> fp16 convert (7 segments) ----------------
__global__ __launch_bounds__(256) void k_cvt_all(
    const float* __restrict__ s0, f16* __restrict__ d0,
    const float* __restrict__ s1, f16* __restrict__ d1,
    const float* __restrict__ s2, f16* __restrict__ d2,
    const float* __restrict__ s3, f16* __restrict__ d3,
    const float* __restrict__ s4, f16* __restrict__ d4,
    const float* __restrict__ s5, f16* __restrict__ d5,
    const float* __restrict__ s6, f16* __restrict__ d6) {
  int bid = blockIdx.x;
  const float* s; f16* d; int base;
  if (bid < 4096)       { s = s0; d = d0; base = bid; }
  else if (bid < 8192)  { s = s1; d = d1; base = bid - 4096; }
  else if (bid < 16384) { s = s2; d = d2; base = bid - 8192; }
  else if (bid < 24576) { s = s3; d = d3; base = bid - 16384; }
  else if (bid < 26624) { s = s4; d = d4; base = bid - 24576; }
  else if (bid < 27648) { s = s5; d = d5; base = bid - 26624; }
  else                  { s = s6; d = d6; base = bid - 27648; }
  int i = (base * 256 + threadIdx.x) * 4;
  float4 v = *(const float4*)(s + i);
  f16x4v o;
  o.x = (f16)v.x; o.y = (f16)v.y; o.z = (f16)v.z; o.w = (f16)v.w;
  *(f16x4v*)(d + i) = o;
}

// ---------------- pack Whh (4096x1024 fp32), K=1024 (kt 0..31) -------------
__global__ __launch_bounds__(256) void k_packw1(const float* __restrict__ Wa,
                                                const float* __restrict__ Wm,
                                                f16* __restrict__ Pa,
                                                f16* __restrict__ Pm) {
  const float* W = blockIdx.y ? Wm : Wa;
  f16* P = blockIdx.y ? Pm : Pa;
  int i2 = blockIdx.x * 256 + threadIdx.x;
  int l = i2 & 63, frag = i2 >> 6;
  int kt = frag & 31, ug = frag >> 5;
  int gate = ug & 3, ut = ug >> 2;
  int row = gate * 1024 + ut * 16 + (l & 15);
  int k = kt * 32 + 8 * (l >> 4);
  const float* s = W + row * 1024 + k;
  f16x8 o;
#pragma unroll
  for (int j = 0; j < 8; ++j) o[j] = (f16)s[j];
  *(f16x8*)(P + frag * 512 + l * 8) = o;
}

// ---------------- pack [Wih_2 | Whh_2] as K=2048 (kt 0..63) ----------------
__global__ __launch_bounds__(256) void k_packw2(const float* __restrict__ Wiha,
                                                const float* __restrict__ Whha,
                                                const float* __restrict__ Wihm,
                                                const float* __restrict__ Whhm,
                                                f16* __restrict__ Pa,
                                                f16* __restrict__ Pm) {
  const float* Wih = blockIdx.y ? Wihm : Wiha;
  const float* Whh = blockIdx.y ? Whhm : Whha;
  f16* P = blockIdx.y ? Pm : Pa;
  int i2 = blockIdx.x * 256 + threadIdx.x;
  int l = i2 & 63, frag = i2 >> 6;
  int kt = frag & 63, ug = frag >> 6;
  int gate = ug & 3, ut = ug >> 2;
  int row = gate * 1024 + ut * 16 + (l & 15);
  int k = kt * 32 + 8 * (l >> 4);
  const float* s = (k < 1024) ? (Wih + row * 1024 + k)
                              : (Whh + row * 1024 + (k - 1024));
  f16x8 o;
#pragma unroll
  for (int j = 0; j < 8; ++j) o[j] = (f16)s[j];
  *(f16x8*)(P + frag * 512 + l * 8) = o;
}

// ---------------- big GEMM: C = A @ B^T + (bi+bh), fp16 out ----------------
template <int NKT, int LDA>
__global__ __launch_bounds__(256) void k_igemm(
    const f16* __restrict__ A0, const f16* __restrict__ A1,
    const f16* __restrict__ B0, const f16* __restrict__ B1,
    const float* __restrict__ bi0, const float* __restrict__ bh0,
    const float* __restrict__ bi1, const float* __restrict__ bh1,
    f16* __restrict__ C0, f16* __restrict__ C1) {
  const f16* A = blockIdx.z ? A1 : A0;
  const f16* B = blockIdx.z ? B1 : B0;
  const float* bi = blockIdx.z ? bi1 : bi0;
  const float* bh = blockIdx.z ? bh1 : bh0;
  f16* C = blockIdx.z ? C1 : C0;

  __shared__ alignas(16) f16 As[128 * 64];
  __shared__ alignas(16) f16 Bs[128 * 64];

  int tid = threadIdx.x, l = tid & 63, w = tid >> 6;
  int m0 = blockIdx.x * 128, n0 = blockIdx.y * 128;
  int wm = (w & 1) * 64, wn = (w >> 1) * 64;
  int lr = l & 15, lg = l >> 4;
  int sr = w * 32 + (l >> 3);
  int sc = (l & 7) * 8;

  f32x4 acc[4][4];
  f32x4 zero = {0.f, 0.f, 0.f, 0.f};
#pragma unroll
  for (int mt = 0; mt < 4; ++mt)
#pragma unroll
    for (int nt = 0; nt < 4; ++nt) acc[mt][nt] = zero;

  for (int kt = 0; kt < NKT; ++kt) {
    int k0 = kt * 64;
#pragma unroll
    for (int c2 = 0; c2 < 4; ++c2) {
      GLDS16(A + (size_t)(m0 + sr + c2 * 8) * LDA + k0 + sc, &As[(w * 32 + c2 * 8) * 64]);
      GLDS16(B + (size_t)(n0 + sr + c2 * 8) * LDA + k0 + sc, &Bs[(w * 32 + c2 * 8) * 64]);
    }
    __syncthreads();
#pragma unroll
    for (int ks = 0; ks < 2; ++ks) {
      f16x8 af[4], bf[4];
#pragma unroll
      for (int mt = 0; mt < 4; ++mt)
        af[mt] = *(const f16x8*)&As[(wm + mt * 16 + lr) * 64 + ks * 32 + 8 * lg];
#pragma unroll
      for (int nt = 0; nt < 4; ++nt)
        bf[nt] = *(const f16x8*)&Bs[(wn + nt * 16 + lr) * 64 + ks * 32 + 8 * lg];
#pragma unroll
      for (int mt = 0; mt < 4; ++mt)
#pragma unroll
        for (int nt = 0; nt < 4; ++nt)
          acc[mt][nt] = __builtin_amdgcn_mfma_f32_16x16x32_f16(af[mt], bf[nt], acc[mt][nt], 0, 0, 0);
    }
    __syncthreads();
  }

#pragma unroll
  for (int nt = 0; nt < 4; ++nt) {
    int n = n0 + wn + nt * 16 + lr;
    float bsum = bi[n] + bh[n];
#pragma unroll
    for (int mt = 0; mt < 4; ++mt) {
      int m = m0 + wm + mt * 16 + lg * 4;
#pragma unroll
      for (int r = 0; r < 4; ++r)
        C[(size_t)(m + r) * 4096 + n] = (f16)(acc[mt][nt][r] + bsum);
    }
  }
}

// ---------------- barrier-free dataflow scan, 1 barrier/step ----------------
// 256 blocks = role x 2 streams x 64 unit-groups; 512 thr, 1 block/CU.
// Producer: per-wave vmcnt(0) -> LDS counter -> LAST wave sets 1 block flag
// (no block barrier before flag). Consumer: each wave polls only ITS 8/16
// producer flags then bulk-loads with cached vector loads (no post-poll
// barrier). red/Gs double-buffered -> single __syncthreads per step.
__global__ __launch_bounds__(512, 1) void k_scan2(
    const f16* __restrict__ Wp1_a, const f16* __restrict__ Wp1_m,
    const f16* __restrict__ Wp2_a, const f16* __restrict__ Wp2_m,
    const f16* __restrict__ G_a, const f16* __restrict__ G_m,
    const float* __restrict__ bi2_a, const float* __restrict__ bh2_a,
    const float* __restrict__ bi2_m, const float* __restrict__ bh2_m,
    f16* __restrict__ H1h,            // [s][t][b][u] 2x64x32x1024
    f16* __restrict__ h2c,            // [s][t][b][u] 2x64x32x1024 (compact h2)
    f16* __restrict__ HaHm,           // [(b*64+t)*2048 + s*1024 + u]
    unsigned* __restrict__ flags1,    // [s][t][64] 1 per producer BLOCK, 0-init
    unsigned* __restrict__ flags2) {  // [s][t][64]
  int bi = blockIdx.x;
  int role = bi >> 7, s = (bi >> 6) & 1, ut = bi & 63, u0 = ut * 16;
  int tid = threadIdx.x, l = tid & 63, w = tid >> 6;   // w in [0,8)
  int lr = l & 15, lg = l >> 4;
  const f16* G = s ? G_m : G_a;
  f16* H1s = H1h + (size_t)s * 64 * 32768;
  f16* h2s = h2c + (size_t)s * 64 * 32768;
  f16* H2o = HaHm + s * 1024;

  // weights -> registers, pinned; ALL indices static (rule #20)
  f16x8 wreg[8][4];
  if (role == 0) {
    const f16* Wp = s ? Wp1_m : Wp1_a;
#pragma unroll
    for (int ks = 0; ks < 4; ++ks)
#pragma unroll
      for (int g = 0; g < 4; ++g) {
        wreg[ks][g] = *(const f16x8*)(Wp + (size_t)((ut * 4 + g) * 32 + (w * 4 + ks)) * 512 + l * 8);
        asm volatile("" : "+v"(wreg[ks][g]));
      }
  } else {
    const f16* Wp = s ? Wp2_m : Wp2_a;
#pragma unroll
    for (int ks = 0; ks < 8; ++ks)
#pragma unroll
      for (int g = 0; g < 4; ++g) {
        wreg[ks][g] = *(const f16x8*)(Wp + (size_t)((ut * 4 + g) * 64 + (w * 8 + ks)) * 512 + l * 8);
        asm volatile("" : "+v"(wreg[ks][g]));
      }
  }

  __shared__ alignas(16) float red[2][8][64][33];   // double-buffered
  __shared__ alignas(16) f16 Gs[2][32][4][16];
  __shared__ unsigned wdone[64];                    // per-step wave counters
  if (tid < 64) wdone[tid] = 0;
  __syncthreads();

  // epilogue mapping: 1 cell per thread: (eb, u0+eu)
  int eb = tid >> 4, eu = tid & 15;
  int emt = eb >> 4, elg = (eb >> 2) & 3, er = eb & 3;
  int lred = elg * 16 + eu;
  int idxb = emt * 16 + er;
  float creg = 0.f;
  f32x4 zero = {0.f, 0.f, 0.f, 0.f};

  if (role == 0) {
    // ======================= cell 1: h1 chain =======================
    int pb = tid >> 4, pg2 = (tid >> 2) & 3, p4 = tid & 3;
    int cb = w * 128;
    for (int t = 0; t < 64; ++t) {
      int pp = t & 1;
      f16x4v gfrag = *(const f16x4v*)(G + (size_t)(pb * 64 + t) * 4096 + pg2 * 1024 + u0 + p4 * 4);

      f32x4 acc[2][4];
#pragma unroll
      for (int mt = 0; mt < 2; ++mt)
#pragma unroll
        for (int g = 0; g < 4; ++g) acc[mt][g] = zero;

      if (t > 0) {
        // wave w depends on producer blocks 8w..8w+7 of step t-1
        const unsigned* fp = flags1 + (size_t)(s * 64 + t - 1) * 64 + 8 * w;
        unsigned f;
        do {
          f = (l < 8) ? __hip_atomic_load(fp + l, __ATOMIC_RELAXED,
                                          __HIP_MEMORY_SCOPE_AGENT) : 1u;
        } while (__any(f == 0));
        asm volatile("" ::: "memory");
        __builtin_amdgcn_sched_barrier(0);
        const f16* hp = H1s + (size_t)(t - 1) * 32768;
        f16x8 A0[4], A1[4];
#pragma unroll
        for (int ks = 0; ks < 4; ++ks) {
          int col = cb + ks * 32 + 8 * lg;
          A0[ks] = *(const f16x8*)(hp + lr * 1024 + col);
          A1[ks] = *(const f16x8*)(hp + (16 + lr) * 1024 + col);
        }
#pragma unroll
        for (int ks = 0; ks < 4; ++ks)
#pragma unroll
          for (int g = 0; g < 4; ++g) {
            acc[0][g] = __builtin_amdgcn_mfma_f32_16x16x32_f16(A0[ks], wreg[ks][g], acc[0][g], 0, 0, 0);
            acc[1][g] = __builtin_amdgcn_mfma_f32_16x16x32_f16(A1[ks], wreg[ks][g], acc[1][g], 0, 0, 0);
          }
      }

      *(f16x4v*)&Gs[pp][pb][pg2][p4 * 4] = gfrag;
#pragma unroll
      for (int mt = 0; mt < 2; ++mt)
#pragma unroll
        for (int g = 0; g < 4; ++g)
#pragma unroll
          for (int r = 0; r < 4; ++r)
            red[pp][w][l][(mt * 4 + g) * 4 + r] = acc[mt][g][r];
      __syncthreads();   // the ONLY barrier per step

      float pre[4];
#pragma unroll
      for (int g = 0; g < 4; ++g) {
        int idx = idxb + g * 4;
        pre[g] = red[pp][0][lred][idx] + red[pp][1][lred][idx] +
                 red[pp][2][lred][idx] + red[pp][3][lred][idx] +
                 red[pp][4][lred][idx] + red[pp][5][lred][idx] +
                 red[pp][6][lred][idx] + red[pp][7][lred][idx] +
                 (float)Gs[pp][eb][g][eu];
      }
      float cn = sigf(pre[1]) * creg + sigf(pre[0]) * tanh2(pre[2]);
      creg = cn;
      union { unsigned short us; f16 h; } cv;
      cv.h = (f16)(sigf(pre[3]) * tanh2(cn));
      unsigned ov = (unsigned)__shfl_xor((int)(unsigned)cv.us, 1, 64);
      if (!(tid & 1)) {
        unsigned pkv = ((unsigned)cv.us) | (ov << 16);
        __hip_atomic_store((unsigned*)(H1s + (size_t)t * 32768 + eb * 1024 + u0 + eu), pkv,
                           __ATOMIC_RELAXED, __HIP_MEMORY_SCOPE_AGENT);
      }
      // per-wave drain; LAST wave publishes the block flag
      asm volatile("s_waitcnt vmcnt(0)" ::: "memory");
      if (l == 0) {
        unsigned ret = __hip_atomic_fetch_add(&wdone[t], 1u, __ATOMIC_RELAXED,
                                              __HIP_MEMORY_SCOPE_WORKGROUP);
        if (ret == 7u) {
          asm volatile("" ::: "memory");
          __hip_atomic_store(flags1 + (size_t)(s * 64 + t) * 64 + ut, 1u,
                             __ATOMIC_RELAXED, __HIP_MEMORY_SCOPE_AGENT);
        }
      }
    }
  } else {
    // ======================= cell 2: h2 chain =======================
    const float* bip = s ? bi2_m : bi2_a;
    const float* bhp = s ? bh2_m : bh2_a;
    float b2r[4];
#pragma unroll
    for (int g = 0; g < 4; ++g)
      b2r[g] = bip[g * 1024 + u0 + eu] + bhp[g * 1024 + u0 + eu];
    int cb = (w & 3) * 256;

    for (int t = 0; t < 64; ++t) {
      int pp = t & 1;
      f32x4 acc[2][4];
#pragma unroll
      for (int mt = 0; mt < 2; ++mt)
#pragma unroll
        for (int g = 0; g < 4; ++g) acc[mt][g] = zero;

      if (w < 4) {
        // Wih_2 half: consume h1[t]; depends on 16 producer blocks
        const unsigned* fp = flags1 + (size_t)(s * 64 + t) * 64 + 16 * (w & 3);
        unsigned f;
        do {
          f = (l < 16) ? __hip_atomic_load(fp + l, __ATOMIC_RELAXED,
                                           __HIP_MEMORY_SCOPE_AGENT) : 1u;
        } while (__any(f == 0));
        asm volatile("" ::: "memory");
        __builtin_amdgcn_sched_barrier(0);
        const f16* hp = H1s + (size_t)t * 32768;
        f16x8 A0[4], A1[4], B0[4], B1[4];
#pragma unroll
        for (int ks = 0; ks < 4; ++ks) {
          int c0 = cb + ks * 32 + 8 * lg;
          int c1 = cb + (4 + ks) * 32 + 8 * lg;
          A0[ks] = *(const f16x8*)(hp + lr * 1024 + c0);
          A1[ks] = *(const f16x8*)(hp + (16 + lr) * 1024 + c0);
          B0[ks] = *(const f16x8*)(hp + lr * 1024 + c1);
          B1[ks] = *(const f16x8*)(hp + (16 + lr) * 1024 + c1);
        }
#pragma unroll
        for (int ks = 0; ks < 4; ++ks)
#pragma unroll
          for (int g = 0; g < 4; ++g) {
            acc[0][g] = __builtin_amdgcn_mfma_f32_16x16x32_f16(A0[ks], wreg[ks][g], acc[0][g], 0, 0, 0);
            acc[1][g] = __builtin_amdgcn_mfma_f32_16x16x32_f16(A1[ks], wreg[ks][g], acc[1][g], 0, 0, 0);
          }
#pragma unroll
        for (int ks = 0; ks < 4; ++ks)
#pragma unroll
          for (int g = 0; g < 4; ++g) {
            acc[0][g] = __builtin_amdgcn_mfma_f32_16x16x32_f16(B0[ks], wreg[4 + ks][g], acc[0][g], 0, 0, 0);
            acc[1][g] = __builtin_amdgcn_mfma_f32_16x16x32_f16(B1[ks], wreg[4 + ks][g], acc[1][g], 0, 0, 0);
          }
      } else if (t > 0) {
        // Whh_2 half: consume h2[t-1] (compact copy)
        const unsigned* fp = flags2 + (size_t)(s * 64 + t - 1) * 64 + 16 * (w & 3);
        unsigned f;
        do {
          f = (l < 16) ? __hip_atomic_load(fp + l, __ATOMIC_RELAXED,
                                           __HIP_MEMORY_SCOPE_AGENT) : 1u;
        } while (__any(f == 0));
        asm volatile("" ::: "memory");
        __builtin_amdgcn_sched_barrier(0);
        const f16* hp = h2s + (size_t)(t - 1) * 32768;
        f16x8 A0[4], A1[4], B0[4], B1[4];
#pragma unroll
        for (int ks = 0; ks < 4; ++ks) {
          int c0 = cb + ks * 32 + 8 * lg;
          int c1 = cb + (4 + ks) * 32 + 8 * lg;
          A0[ks] = *(const f16x8*)(hp + lr * 1024 + c0);
          A1[ks] = *(const f16x8*)(hp + (16 + lr) * 1024 + c0);
          B0[ks] = *(const f16x8*)(hp + lr * 1024 + c1);
          B1[ks] = *(const f16x8*)(hp + (16 + lr) * 1024 + c1);
        }
#pragma unroll
        for (int ks = 0; ks < 4; ++ks)
#pragma unroll
          for (int g = 0; g < 4; ++g) {
            acc[0][g] = __builtin_amdgcn_mfma_f32_16x16x32_f16(A0[ks], wreg[ks][g], acc[0][g], 0, 0, 0);
            acc[1][g] = __builtin_amdgcn_mfma_f32_16x16x32_f16(A1[ks], wreg[ks][g], acc[1][g], 0, 0, 0);
          }
#pragma unroll
        for (int ks = 0; ks < 4; ++ks)
#pragma unroll
          for (int g = 0; g < 4; ++g) {
            acc[0][g] = __builtin_amdgcn_mfma_f32_16x16x32_f16(B0[ks], wreg[4 + ks][g], acc[0][g], 0, 0, 0);
            acc[1][g] = __builtin_amdgcn_mfma_f32_16x16x32_f16(B1[ks], wreg[4 + ks][g], acc[1][g], 0, 0, 0);
          }
      }

#pragma unroll
      for (int mt = 0; mt < 2; ++mt)
#pragma unroll
        for (int g = 0; g < 4; ++g)
#pragma unroll
          for (int r = 0; r < 4; ++r)
            red[pp][w][l][(mt * 4 + g) * 4 + r] = acc[mt][g][r];
      __syncthreads();   // the ONLY barrier per step

      float pre[4];
#pragma unroll
      for (int g = 0; g < 4; ++g) {
        int idx = idxb + g * 4;
        pre[g] = red[pp][0][lred][idx] + red[pp][1][lred][idx] +
                 red[pp][2][lred][idx] + red[pp][3][lred][idx] +
                 red[pp][4][lred][idx] + red[pp][5][lred][idx] +
                 red[pp][6][lred][idx] + red[pp][7][lred][idx] + b2r[g];
      }
      float cn = sigf(pre[1]) * creg + sigf(pre[0]) * tanh2(pre[2]);
      creg = cn;
      union { unsigned short us; f16 h; } cv;
      cv.h = (f16)(sigf(pre[3]) * tanh2(cn));
      unsigned ov = (unsigned)__shfl_xor((int)(unsigned)cv.us, 1, 64);
      if (!(tid & 1)) {
        unsigned pkv = ((unsigned)cv.us) | (ov << 16);
        __hip_atomic_store((unsigned*)(h2s + (size_t)t * 32768 + eb * 1024 + u0 + eu), pkv,
                           __ATOMIC_RELAXED, __HIP_MEMORY_SCOPE_AGENT);
        *(unsigned*)(H2o + (size_t)(eb * 64 + t) * 2048 + u0 + eu) = pkv;
      }
      asm volatile("s_waitcnt vmcnt(0)" ::: "memory");
      if (l == 0) {
        unsigned ret = __hip_atomic_fetch_add(&wdone[t], 1u, __ATOMIC_RELAXED,
                                              __HIP_MEMORY_SCOPE_WORKGROUP);
        if (ret == 7u) {
          asm volatile("" ::: "memory");
          __hip_atomic_store(flags2 + (size_t)(s * 64 + t) * 64 + ut, 1u,
                             __ATOMIC_RELAXED, __HIP_MEMORY_SCOPE_AGENT);
        }
      }
    }
  }
}

// ---------------- fusion ----------------------------------------------------
DEV void gemm_phase(const f16* __restrict__ H, int kA0,
                    const f16* __restrict__ Bp, int brs, int nk,
                    f16* As, f16* Bs, int m0, int n0, int w, int l,
                    int wm, int wn, f32x4 (&acc)[4][2]) {
  f32x4 zero = {0.f, 0.f, 0.f, 0.f};
#pragma unroll
  for (int mt = 0; mt < 4; ++mt)
#pragma unroll
    for (int nt = 0; nt < 2; ++nt) acc[mt][nt] = zero;
  int lr = l & 15, lg = l >> 4;
  int sc = (l & 7) * 8;
  for (int kt = 0; kt < nk; ++kt) {
    int ka = kA0 + kt * 64, kb = kt * 64;
#pragma unroll
    for (int c2 = 0; c2 < 4; ++c2)
      GLDS16(H + (size_t)(m0 + w * 32 + c2 * 8 + (l >> 3)) * 2048 + ka + sc,
             As + (w * 32 + c2 * 8) * 64);
#pragma unroll
    for (int c2 = 0; c2 < 2; ++c2)
      GLDS16(Bp + (size_t)(n0 + w * 16 + c2 * 8 + (l >> 3)) * brs + kb + sc,
             Bs + (w * 16 + c2 * 8) * 64);
    __syncthreads();
#pragma unroll
    for (int ks = 0; ks < 2; ++ks) {
      f16x8 af[4], bf[2];
#pragma unroll
      for (int mt = 0; mt < 4; ++mt)
        af[mt] = *(const f16x8*)&As[(wm + mt * 16 + lr) * 64 + ks * 32 + 8 * lg];
#pragma unroll
      for (int nt = 0; nt < 2; ++nt)
        bf[nt] = *(const f16x8*)&Bs[(wn + nt * 16 + lr) * 64 + ks * 32 + 8 * lg];
#pragma unroll
      for (int mt = 0; mt < 4; ++mt)
#pragma unroll
        for (int nt = 0; nt < 2; ++nt)
          acc[mt][nt] = __builtin_amdgcn_mfma_f32_16x16x32_f16(af[mt], bf[nt], acc[mt][nt], 0, 0, 0);
    }
    __syncthreads();
  }
}

__global__ __launch_bounds__(256) void k_fusion(
    const f16* __restrict__ H, const f16* __restrict__ Wg16,
    const f16* __restrict__ Wa16, const f16* __restrict__ Wm16,
    const float* __restrict__ bg, const float* __restrict__ ba,
    const float* __restrict__ bm, float* __restrict__ out) {
  __shared__ alignas(16) f16 As[128 * 64];
  __shared__ alignas(16) f16 Bs[64 * 64];
  int tid = threadIdx.x, l = tid & 63, w = tid >> 6;
  int m0 = blockIdx.x * 128, n0 = blockIdx.y * 64;
  int wm = (w & 1) * 64, wn = (w >> 1) * 32;
  int lr = l & 15, lg = l >> 4;

  f32x4 acc[4][2];
  float ta[4][2][4], tm[4][2][4];

  gemm_phase(H, 0, Wa16, 1024, 16, As, Bs, m0, n0, w, l, wm, wn, acc);
#pragma unroll
  for (int nt = 0; nt < 2; ++nt) {
    float bv = ba[n0 + wn + nt * 16 + lr];
#pragma unroll
    for (int mt = 0; mt < 4; ++mt)
#pragma unroll
      for (int r = 0; r < 4; ++r) ta[mt][nt][r] = tanh2(acc[mt][nt][r] + bv);
  }
  gemm_phase(H, 1024, Wm16, 1024, 16, As, Bs, m0, n0, w, l, wm, wn, acc);
#pragma unroll
  for (int nt = 0; nt < 2; ++nt) {
    float bv = bm[n0 + wn + nt * 16 + lr];
#pragma unroll
    for (int mt = 0; mt < 4; ++mt)
#pragma unroll
      for (int r = 0; r < 4; ++r) tm[mt][nt][r] = tanh2(acc[mt][nt][r] + bv);
  }
  gemm_phase(H, 0, Wg16, 2048, 32, As, Bs, m0, n0, w, l, wm, wn, acc);
#pragma unroll
  for (int nt = 0; nt < 2; ++nt) {
    int n = n0 + wn + nt * 16 + lr;
    float bv = bg[n];
#pragma unroll
    for (int mt = 0; mt < 4; ++mt) {
      int m = m0 + wm + mt * 16 + lg * 4;
#pragma unroll
      for (int r = 0; r < 4; ++r) {
        float g = sigf(acc[mt][nt][r] + bv);
        out[(size_t)(m + r) * 1024 + n] = tm[mt][nt][r] + g * (ta[mt][nt][r] - tm[mt][nt][r]);
      }
    }
  }
}

// ===========================================================================
extern "C" void kernel_launch(void* const* d_in, const int* in_sizes, int n_in,
                              void* d_out, int out_size, void* d_ws, size_t ws_size,
                              hipStream_t stream) {
  const float* xa = (const float*)d_in[0];
  const float* xm = (const float*)d_in[1];
  const float* Wih_1a = (const float*)d_in[2];
  const float* Whh_1a = (const float*)d_in[3];
  const float* bih_1a = (const float*)d_in[4];
  const float* bhh_1a = (const float*)d_in[5];
  const float* Wih_2a = (const float*)d_in[6];
  const float* Whh_2a = (const float*)d_in[7];
  const float* bih_2a = (const float*)d_in[8];
  const float* bhh_2a = (const float*)d_in[9];
  const float* Wih_1m = (const float*)d_in[10];
  const float* Whh_1m = (const float*)d_in[11];
  const float* bih_1m = (const float*)d_in[12];
  const float* bhh_1m = (const float*)d_in[13];
  const float* Wih_2m = (const float*)d_in[14];
  const float* Whh_2m = (const float*)d_in[15];
  const float* bih_2m = (const float*)d_in[16];
  const float* bhh_2m = (const float*)d_in[17];
  const float* Wg = (const float*)d_in[18];
  const float* bg = (const float*)d_in[19];
  const float* Wa = (const float*)d_in[20];
  const float* ba = (const float*)d_in[21];
  const float* Wm = (const float*)d_in[22];
  const float* bm = (const float*)d_in[23];

  char* ws = (char*)d_ws;
  const size_t MB = 1024ull * 1024;
  if (ws_size < 138 * MB) return;  // fail visibly

  f16* x16a    = (f16*)(ws + 0 * MB);     // dead after GEMM A
  f16* x16m    = (f16*)(ws + 8 * MB);     // dead after GEMM A
  f16* W1ih16a = (f16*)(ws + 16 * MB);    // dead after GEMM A
  f16* W1ih16m = (f16*)(ws + 32 * MB);    // dead after GEMM A
  f16* W1p_a   = (f16*)(ws + 48 * MB);
  f16* W1p_m   = (f16*)(ws + 56 * MB);
  f16* W2p_a   = (f16*)(ws + 64 * MB);
  f16* W2p_m   = (f16*)(ws + 80 * MB);
  f16* Wg16    = (f16*)(ws + 96 * MB);
  f16* Wa16    = (f16*)(ws + 100 * MB);
  f16* Wm16    = (f16*)(ws + 102 * MB);
  f16* G0a     = (f16*)(ws + 104 * MB);
  f16* G0m     = (f16*)(ws + 120 * MB);
  unsigned* flags1 = (unsigned*)(ws + 136 * MB);            // 32 KB
  unsigned* flags2 = (unsigned*)(ws + 136 * MB + 32768);    // 32 KB
  // aliases over GEMM-A-dead regions:
  f16* HaHm    = (f16*)(ws + 0 * MB);     // 8 MB over x16a
  f16* H1h     = (f16*)(ws + 8 * MB);     // 8 MB over x16m
  f16* h2c     = (f16*)(ws + 16 * MB);    // 8 MB over W1ih16a

  dim3 B256(256);
  k_cvt_all<<<28672, B256, 0, stream>>>(xa, x16a, xm, x16m, Wih_1a, W1ih16a,
                                        Wih_1m, W1ih16m, Wg, Wg16, Wa, Wa16,
                                        Wm, Wm16);
  k_packw1<<<dim3(2048, 2), B256, 0, stream>>>(Whh_1a, Whh_1m, W1p_a, W1p_m);
  k_packw2<<<dim3(4096, 2), B256, 0, stream>>>(Wih_2a, Whh_2a, Wih_2m, Whh_2m,
                                               W2p_a, W2p_m);
  hipMemsetAsync(flags1, 0, 65536, stream);   // flags1 + flags2

  // GEMM A: G0 = x @ Wih_1^T + (bih_1 + bhh_1)
  k_igemm<32, 2048><<<dim3(16, 32, 2), B256, 0, stream>>>(
      x16a, x16m, W1ih16a, W1ih16m, bih_1a, bhh_1a, bih_1m, bhh_1m, G0a, G0m);

  // barrier-free dataflow scan (both cells, both streams)
  k_scan2<<<256, dim3(512), 0, stream>>>(
      W1p_a, W1p_m, W2p_a, W2p_m, G0a, G0m,
      bih_2a, bhh_2a, bih_2m, bhh_2m, H1h, h2c, HaHm, flags1, flags2);

  k_fusion<<<dim3(16, 16), B256, 0, stream>>>(HaHm, Wg16, Wa16, Wm16, bg, ba,
                                              bm, (float*)d_out);
}

// Round 13
// 815.188 us; speedup vs baseline: 1.0138x; 1.0138x over previous
//
#include <hip/hip_runtime.h>
#include <cstdint>

typedef _Float16 f16;
typedef _Float16 f16x4v __attribute__((ext_vector_type(4)));
typedef _Float16 f16x8 __attribute__((ext_vector_type(8)));
typedef float f32x4 __attribute__((ext_vector_type(4)));

#define DEV static __device__ __forceinline__

// async global->LDS, 16B per lane; LDS dest = wave-uniform base + lane*16
#define GLDS16(gp, lp) __builtin_amdgcn_global_load_lds( \
    (const __attribute__((address_space(1))) void*)(gp), \
    (__attribute__((address_space(3))) void*)(lp), 16, 0, 0)

DEV float sigf(float x) { return 1.0f / (1.0f + __expf(-x)); }
DEV float tanh2(float x) {
  float e = __expf(-2.0f * fabsf(x));
  float t = (1.0f - e) / (1.0f + e);
  return x >= 0.0f ? t : -t;
}

// one wave polls 64 contiguous producer flags (1 dword per lane, agent-scope)
DEV void waitflags(const unsigned* fp, int l) {
  unsigned f;
  do {
    f = __hip_atomic_load(fp + l, __ATOMIC_RELAXED, __HIP_MEMORY_SCOPE_AGENT);
  } while (__any(f == 0));
  asm volatile("" ::: "memory");
  __builtin_amdgcn_sched_barrier(0);
}

// ---------------- merged fp32 -> fp16 convert (7 segments) ----------------
__global__ __launch_bounds__(256) void k_cvt_all(
    const float* __restrict__ s0, f16* __restrict__ d0,
    const float* __restrict__ s1, f16* __restrict__ d1,
    const float* __restrict__ s2, f16* __restrict__ d2,
    const float* __restrict__ s3, f16* __restrict__ d3,
    const float* __restrict__ s4, f16* __restrict__ d4,
    const float* __restrict__ s5, f16* __restrict__ d5,
    const float* __restrict__ s6, f16* __restrict__ d6) {
  int bid = blockIdx.x;
  const float* s; f16* d; int base;
  if (bid < 4096)       { s = s0; d = d0; base = bid; }
  else if (bid < 8192)  { s = s1; d = d1; base = bid - 4096; }
  else if (bid < 16384) { s = s2; d = d2; base = bid - 8192; }
  else if (bid < 24576) { s = s3; d = d3; base = bid - 16384; }
  else if (bid < 26624) { s = s4; d = d4; base = bid - 24576; }
  else if (bid < 27648) { s = s5; d = d5; base = bid - 26624; }
  else                  { s = s6; d = d6; base = bid - 27648; }
  int i = (base * 256 + threadIdx.x) * 4;
  float4 v = *(const float4*)(s + i);
  f16x4v o;
  o.x = (f16)v.x; o.y = (f16)v.y; o.z = (f16)v.z; o.w = (f16)v.w;
  *(f16x4v*)(d + i) = o;
}

// ---------------- pack Whh (4096x1024 fp32), K=1024 (kt 0..31) -------------
__global__ __launch_bounds__(256) void k_packw1(const float* __restrict__ Wa,
                                                const float* __restrict__ Wm,
                                                f16* __restrict__ Pa,
                                                f16* __restrict__ Pm) {
  const float* W = blockIdx.y ? Wm : Wa;
  f16* P = blockIdx.y ? Pm : Pa;
  int i2 = blockIdx.x * 256 + threadIdx.x;
  int l = i2 & 63, frag = i2 >> 6;
  int kt = frag & 31, ug = frag >> 5;
  int gate = ug & 3, ut = ug >> 2;
  int row = gate * 1024 + ut * 16 + (l & 15);
  int k = kt * 32 + 8 * (l >> 4);
  const float* s = W + row * 1024 + k;
  f16x8 o;
#pragma unroll
  for (int j = 0; j < 8; ++j) o[j] = (f16)s[j];
  *(f16x8*)(P + frag * 512 + l * 8) = o;
}

// ---------------- pack [Wih_2 | Whh_2] as K=2048 (kt 0..63) ----------------
__global__ __launch_bounds__(256) void k_packw2(const float* __restrict__ Wiha,
                                                const float* __restrict__ Whha,
                                                const float* __restrict__ Wihm,
                                                const float* __restrict__ Whhm,
                                                f16* __restrict__ Pa,
                                                f16* __restrict__ Pm) {
  const float* Wih = blockIdx.y ? Wihm : Wiha;
  const float* Whh = blockIdx.y ? Whhm : Whha;
  f16* P = blockIdx.y ? Pm : Pa;
  int i2 = blockIdx.x * 256 + threadIdx.x;
  int l = i2 & 63, frag = i2 >> 6;
  int kt = frag & 63, ug = frag >> 6;
  int gate = ug & 3, ut = ug >> 2;
  int row = gate * 1024 + ut * 16 + (l & 15);
  int k = kt * 32 + 8 * (l >> 4);
  const float* s = (k < 1024) ? (Wih + row * 1024 + k)
                              : (Whh + row * 1024 + (k - 1024));
  f16x8 o;
#pragma unroll
  for (int j = 0; j < 8; ++j) o[j] = (f16)s[j];
  *(f16x8*)(P + frag * 512 + l * 8) = o;
}

// ---------------- big GEMM: C = A @ B^T + (bi+bh), fp16 out ----------------
template <int NKT, int LDA>
__global__ __launch_bounds__(256) void k_igemm(
    const f16* __restrict__ A0, const f16* __restrict__ A1,
    const f16* __restrict__ B0, const f16* __restrict__ B1,
    const float* __restrict__ bi0, const float* __restrict__ bh0,
    const float* __restrict__ bi1, const float* __restrict__ bh1,
    f16* __restrict__ C0, f16* __restrict__ C1) {
  const f16* A = blockIdx.z ? A1 : A0;
  const f16* B = blockIdx.z ? B1 : B0;
  const float* bi = blockIdx.z ? bi1 : bi0;
  const float* bh = blockIdx.z ? bh1 : bh0;
  f16* C = blockIdx.z ? C1 : C0;

  __shared__ alignas(16) f16 As[128 * 64];
  __shared__ alignas(16) f16 Bs[128 * 64];

  int tid = threadIdx.x, l = tid & 63, w = tid >> 6;
  int m0 = blockIdx.x * 128, n0 = blockIdx.y * 128;
  int wm = (w & 1) * 64, wn = (w >> 1) * 64;
  int lr = l & 15, lg = l >> 4;
  int sr = w * 32 + (l >> 3);
  int sc = (l & 7) * 8;

  f32x4 acc[4][4];
  f32x4 zero = {0.f, 0.f, 0.f, 0.f};
#pragma unroll
  for (int mt = 0; mt < 4; ++mt)
#pragma unroll
    for (int nt = 0; nt < 4; ++nt) acc[mt][nt] = zero;

  for (int kt = 0; kt < NKT; ++kt) {
    int k0 = kt * 64;
#pragma unroll
    for (int c2 = 0; c2 < 4; ++c2) {
      GLDS16(A + (size_t)(m0 + sr + c2 * 8) * LDA + k0 + sc, &As[(w * 32 + c2 * 8) * 64]);
      GLDS16(B + (size_t)(n0 + sr + c2 * 8) * LDA + k0 + sc, &Bs[(w * 32 + c2 * 8) * 64]);
    }
    __syncthreads();
#pragma unroll
    for (int ks = 0; ks < 2; ++ks) {
      f16x8 af[4], bf[4];
#pragma unroll
      for (int mt = 0; mt < 4; ++mt)
        af[mt] = *(const f16x8*)&As[(wm + mt * 16 + lr) * 64 + ks * 32 + 8 * lg];
#pragma unroll
      for (int nt = 0; nt < 4; ++nt)
        bf[nt] = *(const f16x8*)&Bs[(wn + nt * 16 + lr) * 64 + ks * 32 + 8 * lg];
#pragma unroll
      for (int mt = 0; mt < 4; ++mt)
#pragma unroll
        for (int nt = 0; nt < 4; ++nt)
          acc[mt][nt] = __builtin_amdgcn_mfma_f32_16x16x32_f16(af[mt], bf[nt], acc[mt][nt], 0, 0, 0);
    }
    __syncthreads();
  }

#pragma unroll
  for (int nt = 0; nt < 4; ++nt) {
    int n = n0 + wn + nt * 16 + lr;
    float bsum = bi[n] + bh[n];
#pragma unroll
    for (int mt = 0; mt < 4; ++mt) {
      int m = m0 + wm + mt * 16 + lg * 4;
#pragma unroll
      for (int r = 0; r < 4; ++r)
        C[(size_t)(m + r) * 4096 + n] = (f16)(acc[mt][nt][r] + bsum);
    }
  }
}

// ---------------- dataflow scan: centralized poll, 2 barriers/step ----------
// 256 blocks = role x 2 streams x 64 unit-groups; 512 thr, 1 block/CU.
// wave0 (and wave4) polls the 64 producer flags (1/lane), barrier A, cached
// bulk loads + MFMA, red[pp] write, barrier B, epilogue, h store, per-wave
// vmcnt(0), LDS wdone counter -> LAST wave publishes block flag (no third
// barrier; red/Gs are double-buffered so no WAR barrier needed).
__global__ __launch_bounds__(512, 1) void k_scan2(
    const f16* __restrict__ Wp1_a, const f16* __restrict__ Wp1_m,
    const f16* __restrict__ Wp2_a, const f16* __restrict__ Wp2_m,
    const f16* __restrict__ G_a, const f16* __restrict__ G_m,
    const float* __restrict__ bi2_a, const float* __restrict__ bh2_a,
    const float* __restrict__ bi2_m, const float* __restrict__ bh2_m,
    f16* __restrict__ H1h,            // [s][t][b][u] 2x64x32x1024
    f16* __restrict__ h2c,            // [s][t][b][u] 2x64x32x1024 (compact h2)
    f16* __restrict__ HaHm,           // [(b*64+t)*2048 + s*1024 + u]
    unsigned* __restrict__ flags1,    // [s][t][64] 1 per producer BLOCK, 0-init
    unsigned* __restrict__ flags2) {  // [s][t][64]
  int bi = blockIdx.x;
  int role = bi >> 7, s = (bi >> 6) & 1, ut = bi & 63, u0 = ut * 16;
  int tid = threadIdx.x, l = tid & 63, w = tid >> 6;   // w in [0,8)
  int lr = l & 15, lg = l >> 4;
  const f16* G = s ? G_m : G_a;
  f16* H1s = H1h + (size_t)s * 64 * 32768;
  f16* h2s = h2c + (size_t)s * 64 * 32768;
  f16* H2o = HaHm + s * 1024;

  // weights -> registers, pinned; ALL indices static (rule #20)
  f16x8 wreg[8][4];
  if (role == 0) {
    const f16* Wp = s ? Wp1_m : Wp1_a;
#pragma unroll
    for (int ks = 0; ks < 4; ++ks)
#pragma unroll
      for (int g = 0; g < 4; ++g) {
        wreg[ks][g] = *(const f16x8*)(Wp + (size_t)((ut * 4 + g) * 32 + (w * 4 + ks)) * 512 + l * 8);
        asm volatile("" : "+v"(wreg[ks][g]));
      }
  } else {
    const f16* Wp = s ? Wp2_m : Wp2_a;
#pragma unroll
    for (int ks = 0; ks < 8; ++ks)
#pragma unroll
      for (int g = 0; g < 4; ++g) {
        wreg[ks][g] = *(const f16x8*)(Wp + (size_t)((ut * 4 + g) * 64 + (w * 8 + ks)) * 512 + l * 8);
        asm volatile("" : "+v"(wreg[ks][g]));
      }
  }

  __shared__ alignas(16) float red[2][8][64][33];   // double-buffered
  __shared__ alignas(16) f16 Gs[2][32][4][16];
  __shared__ unsigned wdone[64];                    // per-step wave counters
  if (tid < 64) wdone[tid] = 0;
  __syncthreads();

  // epilogue mapping: 1 cell per thread: (eb, u0+eu)
  int eb = tid >> 4, eu = tid & 15;
  int emt = eb >> 4, elg = (eb >> 2) & 3, er = eb & 3;
  int lred = elg * 16 + eu;
  int idxb = emt * 16 + er;
  float creg = 0.f;
  f32x4 zero = {0.f, 0.f, 0.f, 0.f};

  if (role == 0) {
    // ======================= cell 1: h1 chain =======================
    int pb = tid >> 4, pg2 = (tid >> 2) & 3, p4 = tid & 3;
    int cb = w * 128;
    for (int t = 0; t < 64; ++t) {
      int pp = t & 1;
      f16x4v gfrag = *(const f16x4v*)(G + (size_t)(pb * 64 + t) * 4096 + pg2 * 1024 + u0 + p4 * 4);

      f32x4 acc[2][4];
#pragma unroll
      for (int mt = 0; mt < 2; ++mt)
#pragma unroll
        for (int g = 0; g < 4; ++g) acc[mt][g] = zero;

      if (t > 0) {
        if (w == 0) waitflags(flags1 + (size_t)(s * 64 + t - 1) * 64, l);
        __syncthreads();   // barrier A: all waves ordered after flag obs
        const f16* hp = H1s + (size_t)(t - 1) * 32768;
        f16x8 A0[4], A1[4];
#pragma unroll
        for (int ks = 0; ks < 4; ++ks) {
          int col = cb + ks * 32 + 8 * lg;
          A0[ks] = *(const f16x8*)(hp + lr * 1024 + col);
          A1[ks] = *(const f16x8*)(hp + (16 + lr) * 1024 + col);
        }
#pragma unroll
        for (int ks = 0; ks < 4; ++ks)
#pragma unroll
          for (int g = 0; g < 4; ++g) {
            acc[0][g] = __builtin_amdgcn_mfma_f32_16x16x32_f16(A0[ks], wreg[ks][g], acc[0][g], 0, 0, 0);
            acc[1][g] = __builtin_amdgcn_mfma_f32_16x16x32_f16(A1[ks], wreg[ks][g], acc[1][g], 0, 0, 0);
          }
      }

      *(f16x4v*)&Gs[pp][pb][pg2][p4 * 4] = gfrag;
#pragma unroll
      for (int mt = 0; mt < 2; ++mt)
#pragma unroll
        for (int g = 0; g < 4; ++g)
#pragma unroll
          for (int r = 0; r < 4; ++r)
            red[pp][w][l][(mt * 4 + g) * 4 + r] = acc[mt][g][r];
      __syncthreads();   // barrier B: before epilogue reads

      float pre[4];
#pragma unroll
      for (int g = 0; g < 4; ++g) {
        int idx = idxb + g * 4;
        pre[g] = red[pp][0][lred][idx] + red[pp][1][lred][idx] +
                 red[pp][2][lred][idx] + red[pp][3][lred][idx] +
                 red[pp][4][lred][idx] + red[pp][5][lred][idx] +
                 red[pp][6][lred][idx] + red[pp][7][lred][idx] +
                 (float)Gs[pp][eb][g][eu];
      }
      float cn = sigf(pre[1]) * creg + sigf(pre[0]) * tanh2(pre[2]);
      creg = cn;
      union { unsigned short us; f16 h; } cv;
      cv.h = (f16)(sigf(pre[3]) * tanh2(cn));
      unsigned ov = (unsigned)__shfl_xor((int)(unsigned)cv.us, 1, 64);
      if (!(tid & 1)) {
        unsigned pkv = ((unsigned)cv.us) | (ov << 16);
        __hip_atomic_store((unsigned*)(H1s + (size_t)t * 32768 + eb * 1024 + u0 + eu), pkv,
                           __ATOMIC_RELAXED, __HIP_MEMORY_SCOPE_AGENT);
      }
      // per-wave drain; LAST wave publishes the block flag
      asm volatile("s_waitcnt vmcnt(0)" ::: "memory");
      if (l == 0) {
        unsigned ret = __hip_atomic_fetch_add(&wdone[t], 1u, __ATOMIC_RELAXED,
                                              __HIP_MEMORY_SCOPE_WORKGROUP);
        if (ret == 7u) {
          asm volatile("" ::: "memory");
          __hip_atomic_store(flags1 + (size_t)(s * 64 + t) * 64 + ut, 1u,
                             __ATOMIC_RELAXED, __HIP_MEMORY_SCOPE_AGENT);
        }
      }
    }
  } else {
    // ======================= cell 2: h2 chain =======================
    const float* bip = s ? bi2_m : bi2_a;
    const float* bhp = s ? bh2_m : bh2_a;
    float b2r[4];
#pragma unroll
    for (int g = 0; g < 4; ++g)
      b2r[g] = bip[g * 1024 + u0 + eu] + bhp[g * 1024 + u0 + eu];
    int cb = (w & 3) * 256;

    for (int t = 0; t < 64; ++t) {
      int pp = t & 1;
      f32x4 acc[2][4];
#pragma unroll
      for (int mt = 0; mt < 2; ++mt)
#pragma unroll
        for (int g = 0; g < 4; ++g) acc[mt][g] = zero;

      if (w == 0) waitflags(flags1 + (size_t)(s * 64 + t) * 64, l);
      if (t > 0 && w == 4) waitflags(flags2 + (size_t)(s * 64 + t - 1) * 64, l);
      __syncthreads();   // barrier A

      if (w < 4) {
        const f16* hp = H1s + (size_t)t * 32768;
        f16x8 A0[4], A1[4], B0[4], B1[4];
#pragma unroll
        for (int ks = 0; ks < 4; ++ks) {
          int c0 = cb + ks * 32 + 8 * lg;
          int c1 = cb + (4 + ks) * 32 + 8 * lg;
          A0[ks] = *(const f16x8*)(hp + lr * 1024 + c0);
          A1[ks] = *(const f16x8*)(hp + (16 + lr) * 1024 + c0);
          B0[ks] = *(const f16x8*)(hp + lr * 1024 + c1);
          B1[ks] = *(const f16x8*)(hp + (16 + lr) * 1024 + c1);
        }
#pragma unroll
        for (int ks = 0; ks < 4; ++ks)
#pragma unroll
          for (int g = 0; g < 4; ++g) {
            acc[0][g] = __builtin_amdgcn_mfma_f32_16x16x32_f16(A0[ks], wreg[ks][g], acc[0][g], 0, 0, 0);
            acc[1][g] = __builtin_amdgcn_mfma_f32_16x16x32_f16(A1[ks], wreg[ks][g], acc[1][g], 0, 0, 0);
          }
#pragma unroll
        for (int ks = 0; ks < 4; ++ks)
#pragma unroll
          for (int g = 0; g < 4; ++g) {
            acc[0][g] = __builtin_amdgcn_mfma_f32_16x16x32_f16(B0[ks], wreg[4 + ks][g], acc[0][g], 0, 0, 0);
            acc[1][g] = __builtin_amdgcn_mfma_f32_16x16x32_f16(B1[ks], wreg[4 + ks][g], acc[1][g], 0, 0, 0);
          }
      } else if (t > 0) {
        const f16* hp = h2s + (size_t)(t - 1) * 32768;
        f16x8 A0[4], A1[4], B0[4], B1[4];
#pragma unroll
        for (int ks = 0; ks < 4; ++ks) {
          int c0 = cb + ks * 32 + 8 * lg;
          int c1 = cb + (4 + ks) * 32 + 8 * lg;
          A0[ks] = *(const f16x8*)(hp + lr * 1024 + c0);
          A1[ks] = *(const f16x8*)(hp + (16 + lr) * 1024 + c0);
          B0[ks] = *(const f16x8*)(hp + lr * 1024 + c1);
          B1[ks] = *(const f16x8*)(hp + (16 + lr) * 1024 + c1);
        }
#pragma unroll
        for (int ks = 0; ks < 4; ++ks)
#pragma unroll
          for (int g = 0; g < 4; ++g) {
            acc[0][g] = __builtin_amdgcn_mfma_f32_16x16x32_f16(A0[ks], wreg[ks][g], acc[0][g], 0, 0, 0);
            acc[1][g] = __builtin_amdgcn_mfma_f32_16x16x32_f16(A1[ks], wreg[ks][g], acc[1][g], 0, 0, 0);
          }
#pragma unroll
        for (int ks = 0; ks < 4; ++ks)
#pragma unroll
          for (int g = 0; g < 4; ++g) {
            acc[0][g] = __builtin_amdgcn_mfma_f32_16x16x32_f16(B0[ks], wreg[4 + ks][g], acc[0][g], 0, 0, 0);
            acc[1][g] = __builtin_amdgcn_mfma_f32_16x16x32_f16(B1[ks], wreg[4 + ks][g], acc[1][g], 0, 0, 0);
          }
      }

#pragma unroll
      for (int mt = 0; mt < 2; ++mt)
#pragma unroll
        for (int g = 0; g < 4; ++g)
#pragma unroll
          for (int r = 0; r < 4; ++r)
            red[pp][w][l][(mt * 4 + g) * 4 + r] = acc[mt][g][r];
      __syncthreads();   // barrier B

      float pre[4];
#pragma unroll
      for (int g = 0; g < 4; ++g) {
        int idx = idxb + g * 4;
        pre[g] = red[pp][0][lred][idx] + red[pp][1][lred][idx] +
                 red[pp][2][lred][idx] + red[pp][3][lred][idx] +
                 red[pp][4][lred][idx] + red[pp][5][lred][idx] +
                 red[pp][6][lred][idx] + red[pp][7][lred][idx] + b2r[g];
      }
      float cn = sigf(pre[1]) * creg + sigf(pre[0]) * tanh2(pre[2]);
      creg = cn;
      union { unsigned short us; f16 h; } cv;
      cv.h = (f16)(sigf(pre[3]) * tanh2(cn));
      unsigned ov = (unsigned)__shfl_xor((int)(unsigned)cv.us, 1, 64);
      if (!(tid & 1)) {
        unsigned pkv = ((unsigned)cv.us) | (ov << 16);
        __hip_atomic_store((unsigned*)(h2s + (size_t)t * 32768 + eb * 1024 + u0 + eu), pkv,
                           __ATOMIC_RELAXED, __HIP_MEMORY_SCOPE_AGENT);
        *(unsigned*)(H2o + (size_t)(eb * 64 + t) * 2048 + u0 + eu) = pkv;
      }
      asm volatile("s_waitcnt vmcnt(0)" ::: "memory");
      if (l == 0) {
        unsigned ret = __hip_atomic_fetch_add(&wdone[t], 1u, __ATOMIC_RELAXED,
                                              __HIP_MEMORY_SCOPE_WORKGROUP);
        if (ret == 7u) {
          asm volatile("" ::: "memory");
          __hip_atomic_store(flags2 + (size_t)(s * 64 + t) * 64 + ut, 1u,
                             __ATOMIC_RELAXED, __HIP_MEMORY_SCOPE_AGENT);
        }
      }
    }
  }
}

// ---------------- fusion ----------------------------------------------------
DEV void gemm_phase(const f16* __restrict__ H, int kA0,
                    const f16* __restrict__ Bp, int brs, int nk,
                    f16* As, f16* Bs, int m0, int n0, int w, int l,
                    int wm, int wn, f32x4 (&acc)[4][2]) {
  f32x4 zero = {0.f, 0.f, 0.f, 0.f};
#pragma unroll
  for (int mt = 0; mt < 4; ++mt)
#pragma unroll
    for (int nt = 0; nt < 2; ++nt) acc[mt][nt] = zero;
  int lr = l & 15, lg = l >> 4;
  int sc = (l & 7) * 8;
  for (int kt = 0; kt < nk; ++kt) {
    int ka = kA0 + kt * 64, kb = kt * 64;
#pragma unroll
    for (int c2 = 0; c2 < 4; ++c2)
      GLDS16(H + (size_t)(m0 + w * 32 + c2 * 8 + (l >> 3)) * 2048 + ka + sc,
             As + (w * 32 + c2 * 8) * 64);
#pragma unroll
    for (int c2 = 0; c2 < 2; ++c2)
      GLDS16(Bp + (size_t)(n0 + w * 16 + c2 * 8 + (l >> 3)) * brs + kb + sc,
             Bs + (w * 16 + c2 * 8) * 64);
    __syncthreads();
#pragma unroll
    for (int ks = 0; ks < 2; ++ks) {
      f16x8 af[4], bf[2];
#pragma unroll
      for (int mt = 0; mt < 4; ++mt)
        af[mt] = *(const f16x8*)&As[(wm + mt * 16 + lr) * 64 + ks * 32 + 8 * lg];
#pragma unroll
      for (int nt = 0; nt < 2; ++nt)
        bf[nt] = *(const f16x8*)&Bs[(wn + nt * 16 + lr) * 64 + ks * 32 + 8 * lg];
#pragma unroll
      for (int mt = 0; mt < 4; ++mt)
#pragma unroll
        for (int nt = 0; nt < 2; ++nt)
          acc[mt][nt] = __builtin_amdgcn_mfma_f32_16x16x32_f16(af[mt], bf[nt], acc[mt][nt], 0, 0, 0);
    }
    __syncthreads();
  }
}

__global__ __launch_bounds__(256) void k_fusion(
    const f16* __restrict__ H, const f16* __restrict__ Wg16,
    const f16* __restrict__ Wa16, const f16* __restrict__ Wm16,
    const float* __restrict__ bg, const float* __restrict__ ba,
    const float* __restrict__ bm, float* __restrict__ out) {
  __shared__ alignas(16) f16 As[128 * 64];
  __shared__ alignas(16) f16 Bs[64 * 64];
  int tid = threadIdx.x, l = tid & 63, w = tid >> 6;
  int m0 = blockIdx.x * 128, n0 = blockIdx.y * 64;
  int wm = (w & 1) * 64, wn = (w >> 1) * 32;
  int lr = l & 15, lg = l >> 4;

  f32x4 acc[4][2];
  float ta[4][2][4], tm[4][2][4];

  gemm_phase(H, 0, Wa16, 1024, 16, As, Bs, m0, n0, w, l, wm, wn, acc);
#pragma unroll
  for (int nt = 0; nt < 2; ++nt) {
    float bv = ba[n0 + wn + nt * 16 + lr];
#pragma unroll
    for (int mt = 0; mt < 4; ++mt)
#pragma unroll
      for (int r = 0; r < 4; ++r) ta[mt][nt][r] = tanh2(acc[mt][nt][r] + bv);
  }
  gemm_phase(H, 1024, Wm16, 1024, 16, As, Bs, m0, n0, w, l, wm, wn, acc);
#pragma unroll
  for (int nt = 0; nt < 2; ++nt) {
    float bv = bm[n0 + wn + nt * 16 + lr];
#pragma unroll
    for (int mt = 0; mt < 4; ++mt)
#pragma unroll
      for (int r = 0; r < 4; ++r) tm[mt][nt][r] = tanh2(acc[mt][nt][r] + bv);
  }
  gemm_phase(H, 0, Wg16, 2048, 32, As, Bs, m0, n0, w, l, wm, wn, acc);
#pragma unroll
  for (int nt = 0; nt < 2; ++nt) {
    int n = n0 + wn + nt * 16 + lr;
    float bv = bg[n];
#pragma unroll
    for (int mt = 0; mt < 4; ++mt) {
      int m = m0 + wm + mt * 16 + lg * 4;
#pragma unroll
      for (int r = 0; r < 4; ++r) {
        float g = sigf(acc[mt][nt][r] + bv);
        out[(size_t)(m + r) * 1024 + n] = tm[mt][nt][r] + g * (ta[mt][nt][r] - tm[mt][nt][r]);
      }
    }
  }
}

// ===========================================================================
extern "C" void kernel_launch(void* const* d_in, const int* in_sizes, int n_in,
                              void* d_out, int out_size, void* d_ws, size_t ws_size,
                              hipStream_t stream) {
  const float* xa = (const float*)d_in[0];
  const float* xm = (const float*)d_in[1];
  const float* Wih_1a = (const float*)d_in[2];
  const float* Whh_1a = (const float*)d_in[3];
  const float* bih_1a = (const float*)d_in[4];
  const float* bhh_1a = (const float*)d_in[5];
  const float* Wih_2a = (const float*)d_in[6];
  const float* Whh_2a = (const float*)d_in[7];
  const float* bih_2a = (const float*)d_in[8];
  const float* bhh_2a = (const float*)d_in[9];
  const float* Wih_1m = (const float*)d_in[10];
  const float* Whh_1m = (const float*)d_in[11];
  const float* bih_1m = (const float*)d_in[12];
  const float* bhh_1m = (const float*)d_in[13];
  const float* Wih_2m = (const float*)d_in[14];
  const float* Whh_2m = (const float*)d_in[15];
  const float* bih_2m = (const float*)d_in[16];
  const float* bhh_2m = (const float*)d_in[17];
  const float* Wg = (const float*)d_in[18];
  const float* bg = (const float*)d_in[19];
  const float* Wa = (const float*)d_in[20];
  const float* ba = (const float*)d_in[21];
  const float* Wm = (const float*)d_in[22];
  const float* bm = (const float*)d_in[23];

  char* ws = (char*)d_ws;
  const size_t MB = 1024ull * 1024;
  if (ws_size < 138 * MB) return;  // fail visibly

  f16* x16a    = (f16*)(ws + 0 * MB);     // dead after GEMM A
  f16* x16m    = (f16*)(ws + 8 * MB);     // dead after GEMM A
  f16* W1ih16a = (f16*)(ws + 16 * MB);    // dead after GEMM A
  f16* W1ih16m = (f16*)(ws + 32 * MB);    // dead after GEMM A
  f16* W1p_a   = (f16*)(ws + 48 * MB);
  f16* W1p_m   = (f16*)(ws + 56 * MB);
  f16* W2p_a   = (f16*)(ws + 64 * MB);
  f16* W2p_m   = (f16*)(ws + 80 * MB);
  f16* Wg16    = (f16*)(ws + 96 * MB);
  f16* Wa16    = (f16*)(ws + 100 * MB);
  f16* Wm16    = (f16*)(ws + 102 * MB);
  f16* G0a     = (f16*)(ws + 104 * MB);
  f16* G0m     = (f16*)(ws + 120 * MB);
  unsigned* flags1 = (unsigned*)(ws + 136 * MB);            // 32 KB
  unsigned* flags2 = (unsigned*)(ws + 136 * MB + 32768);    // 32 KB
  // aliases over GEMM-A-dead regions:
  f16* HaHm    = (f16*)(ws + 0 * MB);     // 8 MB over x16a
  f16* H1h     = (f16*)(ws + 8 * MB);     // 8 MB over x16m
  f16* h2c     = (f16*)(ws + 16 * MB);    // 8 MB over W1ih16a

  dim3 B256(256);
  k_cvt_all<<<28672, B256, 0, stream>>>(xa, x16a, xm, x16m, Wih_1a, W1ih16a,
                                        Wih_1m, W1ih16m, Wg, Wg16, Wa, Wa16,
                                        Wm, Wm16);
  k_packw1<<<dim3(2048, 2), B256, 0, stream>>>(Whh_1a, Whh_1m, W1p_a, W1p_m);
  k_packw2<<<dim3(4096, 2), B256, 0, stream>>>(Wih_2a, Whh_2a, Wih_2m, Whh_2m,
                                               W2p_a, W2p_m);
  hipMemsetAsync(flags1, 0, 65536, stream);   // flags1 + flags2

  // GEMM A: G0 = x @ Wih_1^T + (bih_1 + bhh_1)
  k_igemm<32, 2048><<<dim3(16, 32, 2), B256, 0, stream>>>(
      x16a, x16m, W1ih16a, W1ih16m, bih_1a, bhh_1a, bih_1m, bhh_1m, G0a, G0m);

  // dataflow scan (both cells, both streams)
  k_scan2<<<256, dim3(512), 0, stream>>>(
      W1p_a, W1p_m, W2p_a, W2p_m, G0a, G0m,
      bih_2a, bhh_2a, bih_2m, bhh_2m, H1h, h2c, HaHm, flags1, flags2);

  k_fusion<<<dim3(16, 16), B256, 0, stream>>>(HaHm, Wg16, Wa16, Wm16, bg, ba,
                                              bm, (float*)d_out);
}

// Round 14
// 729.837 us; speedup vs baseline: 1.1323x; 1.1169x over previous
//
#include <hip/hip_runtime.h>
#include <cstdint>

typedef _Float16 f16;
typedef _Float16 f16x4v __attribute__((ext_vector_type(4)));
typedef _Float16 f16x8 __attribute__((ext_vector_type(8)));
typedef float f32x4 __attribute__((ext_vector_type(4)));

#define DEV static __device__ __forceinline__

// async global->LDS, 16B per lane; LDS dest = wave-uniform base + lane*16
#define GLDS16(gp, lp) __builtin_amdgcn_global_load_lds( \
    (const __attribute__((address_space(1))) void*)(gp), \
    (__attribute__((address_space(3))) void*)(lp), 16, 0, 0)

DEV float sigf(float x) { return 1.0f / (1.0f + __expf(-x)); }
DEV float tanh2(float x) {
  float e = __expf(-2.0f * fabsf(x));
  float t = (1.0f - e) / (1.0f + e);
  return x >= 0.0f ? t : -t;
}

// one wave polls 64 contiguous producer flags (1 dword per lane, agent-scope)
DEV void waitflags(const unsigned* fp, int l) {
  unsigned f;
  do {
    f = __hip_atomic_load(fp + l, __ATOMIC_RELAXED, __HIP_MEMORY_SCOPE_AGENT);
  } while (__any(f == 0));
  asm volatile("" ::: "memory");
  __builtin_amdgcn_sched_barrier(0);
}

// ---------------- merged fp32 -> fp16 convert (7 segments) ----------------
__global__ __launch_bounds__(256) void k_cvt_all(
    const float* __restrict__ s0, f16* __restrict__ d0,
    const float* __restrict__ s1, f16* __restrict__ d1,
    const float* __restrict__ s2, f16* __restrict__ d2,
    const float* __restrict__ s3, f16* __restrict__ d3,
    const float* __restrict__ s4, f16* __restrict__ d4,
    const float* __restrict__ s5, f16* __restrict__ d5,
    const float* __restrict__ s6, f16* __restrict__ d6) {
  int bid = blockIdx.x;
  const float* s; f16* d; int base;
  if (bid < 4096)       { s = s0; d = d0; base = bid; }
  else if (bid < 8192)  { s = s1; d = d1; base = bid - 4096; }
  else if (bid < 16384) { s = s2; d = d2; base = bid - 8192; }
  else if (bid < 24576) { s = s3; d = d3; base = bid - 16384; }
  else if (bid < 26624) { s = s4; d = d4; base = bid - 24576; }
  else if (bid < 27648) { s = s5; d = d5; base = bid - 26624; }
  else                  { s = s6; d = d6; base = bid - 27648; }
  int i = (base * 256 + threadIdx.x) * 4;
  float4 v = *(const float4*)(s + i);
  f16x4v o;
  o.x = (f16)v.x; o.y = (f16)v.y; o.z = (f16)v.z; o.w = (f16)v.w;
  *(f16x4v*)(d + i) = o;
}

// ---------------- pack Whh (4096x1024 fp32), K=1024 (kt 0..31) -------------
__global__ __launch_bounds__(256) void k_packw1(const float* __restrict__ Wa,
                                                const float* __restrict__ Wm,
                                                f16* __restrict__ Pa,
                                                f16* __restrict__ Pm) {
  const float* W = blockIdx.y ? Wm : Wa;
  f16* P = blockIdx.y ? Pm : Pa;
  int i2 = blockIdx.x * 256 + threadIdx.x;
  int l = i2 & 63, frag = i2 >> 6;
  int kt = frag & 31, ug = frag >> 5;
  int gate = ug & 3, ut = ug >> 2;
  int row = gate * 1024 + ut * 16 + (l & 15);
  int k = kt * 32 + 8 * (l >> 4);
  const float* s = W + row * 1024 + k;
  f16x8 o;
#pragma unroll
  for (int j = 0; j < 8; ++j) o[j] = (f16)s[j];
  *(f16x8*)(P + frag * 512 + l * 8) = o;
}

// ---------------- pack [Wih_2 | Whh_2] as K=2048 (kt 0..63) ----------------
__global__ __launch_bounds__(256) void k_packw2(const float* __restrict__ Wiha,
                                                const float* __restrict__ Whha,
                                                const float* __restrict__ Wihm,
                                                const float* __restrict__ Whhm,
                                                f16* __restrict__ Pa,
                                                f16* __restrict__ Pm) {
  const float* Wih = blockIdx.y ? Wihm : Wiha;
  const float* Whh = blockIdx.y ? Whhm : Whha;
  f16* P = blockIdx.y ? Pm : Pa;
  int i2 = blockIdx.x * 256 + threadIdx.x;
  int l = i2 & 63, frag = i2 >> 6;
  int kt = frag & 63, ug = frag >> 6;
  int gate = ug & 3, ut = ug >> 2;
  int row = gate * 1024 + ut * 16 + (l & 15);
  int k = kt * 32 + 8 * (l >> 4);
  const float* s = (k < 1024) ? (Wih + row * 1024 + k)
                              : (Whh + row * 1024 + (k - 1024));
  f16x8 o;
#pragma unroll
  for (int j = 0; j < 8; ++j) o[j] = (f16)s[j];
  *(f16x8*)(P + frag * 512 + l * 8) = o;
}

// ---------------- big GEMM: C = A @ B^T + (bi+bh), fp16 out ----------------
template <int NKT, int LDA>
__global__ __launch_bounds__(256) void k_igemm(
    const f16* __restrict__ A0, const f16* __restrict__ A1,
    const f16* __restrict__ B0, const f16* __restrict__ B1,
    const float* __restrict__ bi0, const float* __restrict__ bh0,
    const float* __restrict__ bi1, const float* __restrict__ bh1,
    f16* __restrict__ C0, f16* __restrict__ C1) {
  const f16* A = blockIdx.z ? A1 : A0;
  const f16* B = blockIdx.z ? B1 : B0;
  const float* bi = blockIdx.z ? bi1 : bi0;
  const float* bh = blockIdx.z ? bh1 : bh0;
  f16* C = blockIdx.z ? C1 : C0;

  __shared__ alignas(16) f16 As[128 * 64];
  __shared__ alignas(16) f16 Bs[128 * 64];

  int tid = threadIdx.x, l = tid & 63, w = tid >> 6;
  int m0 = blockIdx.x * 128, n0 = blockIdx.y * 128;
  int wm = (w & 1) * 64, wn = (w >> 1) * 64;
  int lr = l & 15, lg = l >> 4;
  int sr = w * 32 + (l >> 3);
  int sc = (l & 7) * 8;

  f32x4 acc[4][4];
  f32x4 zero = {0.f, 0.f, 0.f, 0.f};
#pragma unroll
  for (int mt = 0; mt < 4; ++mt)
#pragma unroll
    for (int nt = 0; nt < 4; ++nt) acc[mt][nt] = zero;

  for (int kt = 0; kt < NKT; ++kt) {
    int k0 = kt * 64;
#pragma unroll
    for (int c2 = 0; c2 < 4; ++c2) {
      GLDS16(A + (size_t)(m0 + sr + c2 * 8) * LDA + k0 + sc, &As[(w * 32 + c2 * 8) * 64]);
      GLDS16(B + (size_t)(n0 + sr + c2 * 8) * LDA + k0 + sc, &Bs[(w * 32 + c2 * 8) * 64]);
    }
    __syncthreads();
#pragma unroll
    for (int ks = 0; ks < 2; ++ks) {
      f16x8 af[4], bf[4];
#pragma unroll
      for (int mt = 0; mt < 4; ++mt)
        af[mt] = *(const f16x8*)&As[(wm + mt * 16 + lr) * 64 + ks * 32 + 8 * lg];
#pragma unroll
      for (int nt = 0; nt < 4; ++nt)
        bf[nt] = *(const f16x8*)&Bs[(wn + nt * 16 + lr) * 64 + ks * 32 + 8 * lg];
#pragma unroll
      for (int mt = 0; mt < 4; ++mt)
#pragma unroll
        for (int nt = 0; nt < 4; ++nt)
          acc[mt][nt] = __builtin_amdgcn_mfma_f32_16x16x32_f16(af[mt], bf[nt], acc[mt][nt], 0, 0, 0);
    }
    __syncthreads();
  }

#pragma unroll
  for (int nt = 0; nt < 4; ++nt) {
    int n = n0 + wn + nt * 16 + lr;
    float bsum = bi[n] + bh[n];
#pragma unroll
    for (int mt = 0; mt < 4; ++mt) {
      int m = m0 + wm + mt * 16 + lg * 4;
#pragma unroll
      for (int r = 0; r < 4; ++r)
        C[(size_t)(m + r) * 4096 + n] = (f16)(acc[mt][nt][r] + bsum);
    }
  }
}

// ---------------- dataflow scan (R11-exact): cached bulk loads --------------
// 256 blocks = role(0:cell1,1:cell2) x 2 streams x 64 unit-groups; 512 thr,
// 1 block/CU. Producers: store h (agent atomics), vmcnt(0)+syncthreads, set
// ONE flag. Consumers: wave0/wave4 poll 64 flags (1/lane), syncthreads, then
// bulk-load with NORMAL cached vector loads. This was the measured-best scan
// (527 us); R12/R13's dbuf-red + wdone variants regressed — reverted.
__global__ __launch_bounds__(512, 1) void k_scan2(
    const f16* __restrict__ Wp1_a, const f16* __restrict__ Wp1_m,
    const f16* __restrict__ Wp2_a, const f16* __restrict__ Wp2_m,
    const f16* __restrict__ G_a, const f16* __restrict__ G_m,
    const float* __restrict__ bi2_a, const float* __restrict__ bh2_a,
    const float* __restrict__ bi2_m, const float* __restrict__ bh2_m,
    f16* __restrict__ H1h,            // [s][t][b][u] 2x64x32x1024
    f16* __restrict__ h2c,            // [s][t][b][u] 2x64x32x1024 (compact h2)
    f16* __restrict__ HaHm,           // [(b*64+t)*2048 + s*1024 + u]
    unsigned* __restrict__ flags1,    // [s][t][64] dwords, zeroed
    unsigned* __restrict__ flags2) {  // [s][t][64] dwords, zeroed
  int bi = blockIdx.x;
  int role = bi >> 7, s = (bi >> 6) & 1, ut = bi & 63, u0 = ut * 16;
  int tid = threadIdx.x, l = tid & 63, w = tid >> 6;   // w in [0,8)
  int lr = l & 15, lg = l >> 4;
  const f16* G = s ? G_m : G_a;
  f16* H1s = H1h + (size_t)s * 64 * 32768;
  f16* h2s = h2c + (size_t)s * 64 * 32768;
  f16* H2o = HaHm + s * 1024;

  // weights -> registers, pinned; ALL indices static (rule #20)
  f16x8 wreg[8][4];
  if (role == 0) {
    const f16* Wp = s ? Wp1_m : Wp1_a;
#pragma unroll
    for (int ks = 0; ks < 4; ++ks)
#pragma unroll
      for (int g = 0; g < 4; ++g) {
        wreg[ks][g] = *(const f16x8*)(Wp + (size_t)((ut * 4 + g) * 32 + (w * 4 + ks)) * 512 + l * 8);
        asm volatile("" : "+v"(wreg[ks][g]));
      }
  } else {
    const f16* Wp = s ? Wp2_m : Wp2_a;
#pragma unroll
    for (int ks = 0; ks < 8; ++ks)
#pragma unroll
      for (int g = 0; g < 4; ++g) {
        wreg[ks][g] = *(const f16x8*)(Wp + (size_t)((ut * 4 + g) * 64 + (w * 8 + ks)) * 512 + l * 8);
        asm volatile("" : "+v"(wreg[ks][g]));
      }
  }

  __shared__ alignas(16) float red[8][64][33];
  __shared__ alignas(16) f16 Gs[32][4][16];

  // epilogue mapping: 1 cell per thread: (eb, u0+eu)
  int eb = tid >> 4, eu = tid & 15;
  int emt = eb >> 4, elg = (eb >> 2) & 3, er = eb & 3;
  int lred = elg * 16 + eu;
  int idxb = emt * 16 + er;
  float creg = 0.f;
  f32x4 zero = {0.f, 0.f, 0.f, 0.f};

  if (role == 0) {
    // ======================= cell 1: h1 chain =======================
    int pb = tid >> 4, pg2 = (tid >> 2) & 3, p4 = tid & 3;
    int cb = w * 128;
    for (int t = 0; t < 64; ++t) {
      f16x4v gfrag = *(const f16x4v*)(G + (size_t)(pb * 64 + t) * 4096 + pg2 * 1024 + u0 + p4 * 4);

      f32x4 acc[2][4];
#pragma unroll
      for (int mt = 0; mt < 2; ++mt)
#pragma unroll
        for (int g = 0; g < 4; ++g) acc[mt][g] = zero;

      if (t > 0) {
        if (w == 0) waitflags(flags1 + (size_t)(s * 64 + t - 1) * 64, l);
        __syncthreads();   // all waves ordered after flag observation
        const f16* hp = H1s + (size_t)(t - 1) * 32768;
        f16x8 A0[4], A1[4];
#pragma unroll
        for (int ks = 0; ks < 4; ++ks) {
          int col = cb + ks * 32 + 8 * lg;
          A0[ks] = *(const f16x8*)(hp + lr * 1024 + col);
          A1[ks] = *(const f16x8*)(hp + (16 + lr) * 1024 + col);
        }
#pragma unroll
        for (int ks = 0; ks < 4; ++ks)
#pragma unroll
          for (int g = 0; g < 4; ++g) {
            acc[0][g] = __builtin_amdgcn_mfma_f32_16x16x32_f16(A0[ks], wreg[ks][g], acc[0][g], 0, 0, 0);
            acc[1][g] = __builtin_amdgcn_mfma_f32_16x16x32_f16(A1[ks], wreg[ks][g], acc[1][g], 0, 0, 0);
          }
      }

      *(f16x4v*)&Gs[pb][pg2][p4 * 4] = gfrag;
#pragma unroll
      for (int mt = 0; mt < 2; ++mt)
#pragma unroll
        for (int g = 0; g < 4; ++g)
#pragma unroll
          for (int r = 0; r < 4; ++r)
            red[w][l][(mt * 4 + g) * 4 + r] = acc[mt][g][r];
      __syncthreads();

      float pre[4];
#pragma unroll
      for (int g = 0; g < 4; ++g) {
        int idx = idxb + g * 4;
        pre[g] = red[0][lred][idx] + red[1][lred][idx] + red[2][lred][idx] +
                 red[3][lred][idx] + red[4][lred][idx] + red[5][lred][idx] +
                 red[6][lred][idx] + red[7][lred][idx] + (float)Gs[eb][g][eu];
      }
      float cn = sigf(pre[1]) * creg + sigf(pre[0]) * tanh2(pre[2]);
      creg = cn;
      union { unsigned short us; f16 h; } cv;
      cv.h = (f16)(sigf(pre[3]) * tanh2(cn));
      unsigned ov = (unsigned)__shfl_xor((int)(unsigned)cv.us, 1, 64);
      if (!(tid & 1)) {
        unsigned pkv = ((unsigned)cv.us) | (ov << 16);
        __hip_atomic_store((unsigned*)(H1s + (size_t)t * 32768 + eb * 1024 + u0 + eu), pkv,
                           __ATOMIC_RELAXED, __HIP_MEMORY_SCOPE_AGENT);
      }
      asm volatile("s_waitcnt vmcnt(0)" ::: "memory");
      __syncthreads();   // whole block's h stores drained; also red/Gs WAR
      if (tid == 0)
        __hip_atomic_store(flags1 + (size_t)(s * 64 + t) * 64 + ut, 1u,
                           __ATOMIC_RELAXED, __HIP_MEMORY_SCOPE_AGENT);
    }
  } else {
    // ======================= cell 2: h2 chain =======================
    const float* bip = s ? bi2_m : bi2_a;
    const float* bhp = s ? bh2_m : bh2_a;
    float b2r[4];
#pragma unroll
    for (int g = 0; g < 4; ++g)
      b2r[g] = bip[g * 1024 + u0 + eu] + bhp[g * 1024 + u0 + eu];
    int cb = (w & 3) * 256;

    for (int t = 0; t < 64; ++t) {
      f32x4 acc[2][4];
#pragma unroll
      for (int mt = 0; mt < 2; ++mt)
#pragma unroll
        for (int g = 0; g < 4; ++g) acc[mt][g] = zero;

      // wave 0 polls h1[t] flags; wave 4 polls h2[t-1] flags
      if (w == 0) waitflags(flags1 + (size_t)(s * 64 + t) * 64, l);
      if (t > 0 && w == 4) waitflags(flags2 + (size_t)(s * 64 + t - 1) * 64, l);
      __syncthreads();

      if (w < 4) {
        const f16* hp = H1s + (size_t)t * 32768;
        f16x8 A0[4], A1[4], B0[4], B1[4];
#pragma unroll
        for (int ks = 0; ks < 4; ++ks) {
          int c0 = cb + ks * 32 + 8 * lg;
          int c1 = cb + (4 + ks) * 32 + 8 * lg;
          A0[ks] = *(const f16x8*)(hp + lr * 1024 + c0);
          A1[ks] = *(const f16x8*)(hp + (16 + lr) * 1024 + c0);
          B0[ks] = *(const f16x8*)(hp + lr * 1024 + c1);
          B1[ks] = *(const f16x8*)(hp + (16 + lr) * 1024 + c1);
        }
#pragma unroll
        for (int ks = 0; ks < 4; ++ks)
#pragma unroll
          for (int g = 0; g < 4; ++g) {
            acc[0][g] = __builtin_amdgcn_mfma_f32_16x16x32_f16(A0[ks], wreg[ks][g], acc[0][g], 0, 0, 0);
            acc[1][g] = __builtin_amdgcn_mfma_f32_16x16x32_f16(A1[ks], wreg[ks][g], acc[1][g], 0, 0, 0);
          }
#pragma unroll
        for (int ks = 0; ks < 4; ++ks)
#pragma unroll
          for (int g = 0; g < 4; ++g) {
            acc[0][g] = __builtin_amdgcn_mfma_f32_16x16x32_f16(B0[ks], wreg[4 + ks][g], acc[0][g], 0, 0, 0);
            acc[1][g] = __builtin_amdgcn_mfma_f32_16x16x32_f16(B1[ks], wreg[4 + ks][g], acc[1][g], 0, 0, 0);
          }
      } else if (t > 0) {
        const f16* hp = h2s + (size_t)(t - 1) * 32768;
        f16x8 A0[4], A1[4], B0[4], B1[4];
#pragma unroll
        for (int ks = 0; ks < 4; ++ks) {
          int c0 = cb + ks * 32 + 8 * lg;
          int c1 = cb + (4 + ks) * 32 + 8 * lg;
          A0[ks] = *(const f16x8*)(hp + lr * 1024 + c0);
          A1[ks] = *(const f16x8*)(hp + (16 + lr) * 1024 + c0);
          B0[ks] = *(const f16x8*)(hp + lr * 1024 + c1);
          B1[ks] = *(const f16x8*)(hp + (16 + lr) * 1024 + c1);
        }
#pragma unroll
        for (int ks = 0; ks < 4; ++ks)
#pragma unroll
          for (int g = 0; g < 4; ++g) {
            acc[0][g] = __builtin_amdgcn_mfma_f32_16x16x32_f16(A0[ks], wreg[ks][g], acc[0][g], 0, 0, 0);
            acc[1][g] = __builtin_amdgcn_mfma_f32_16x16x32_f16(A1[ks], wreg[ks][g], acc[1][g], 0, 0, 0);
          }
#pragma unroll
        for (int ks = 0; ks < 4; ++ks)
#pragma unroll
          for (int g = 0; g < 4; ++g) {
            acc[0][g] = __builtin_amdgcn_mfma_f32_16x16x32_f16(B0[ks], wreg[4 + ks][g], acc[0][g], 0, 0, 0);
            acc[1][g] = __builtin_amdgcn_mfma_f32_16x16x32_f16(B1[ks], wreg[4 + ks][g], acc[1][g], 0, 0, 0);
          }
      }

#pragma unroll
      for (int mt = 0; mt < 2; ++mt)
#pragma unroll
        for (int g = 0; g < 4; ++g)
#pragma unroll
          for (int r = 0; r < 4; ++r)
            red[w][l][(mt * 4 + g) * 4 + r] = acc[mt][g][r];
      __syncthreads();

      float pre[4];
#pragma unroll
      for (int g = 0; g < 4; ++g) {
        int idx = idxb + g * 4;
        pre[g] = red[0][lred][idx] + red[1][lred][idx] + red[2][lred][idx] +
                 red[3][lred][idx] + red[4][lred][idx] + red[5][lred][idx] +
                 red[6][lred][idx] + red[7][lred][idx] + b2r[g];
      }
      float cn = sigf(pre[1]) * creg + sigf(pre[0]) * tanh2(pre[2]);
      creg = cn;
      union { unsigned short us; f16 h; } cv;
      cv.h = (f16)(sigf(pre[3]) * tanh2(cn));
      unsigned ov = (unsigned)__shfl_xor((int)(unsigned)cv.us, 1, 64);
      if (!(tid & 1)) {
        unsigned pkv = ((unsigned)cv.us) | (ov << 16);
        __hip_atomic_store((unsigned*)(h2s + (size_t)t * 32768 + eb * 1024 + u0 + eu), pkv,
                           __ATOMIC_RELAXED, __HIP_MEMORY_SCOPE_AGENT);
        *(unsigned*)(H2o + (size_t)(eb * 64 + t) * 2048 + u0 + eu) = pkv;
      }
      asm volatile("s_waitcnt vmcnt(0)" ::: "memory");
      __syncthreads();   // block drained; red WAR
      if (tid == 0)
        __hip_atomic_store(flags2 + (size_t)(s * 64 + t) * 64 + ut, 1u,
                           __ATOMIC_RELAXED, __HIP_MEMORY_SCOPE_AGENT);
    }
  }
}

// ---------------- fusion ----------------------------------------------------
DEV void gemm_phase(const f16* __restrict__ H, int kA0,
                    const f16* __restrict__ Bp, int brs, int nk,
                    f16* As, f16* Bs, int m0, int n0, int w, int l,
                    int wm, int wn, f32x4 (&acc)[4][2]) {
  f32x4 zero = {0.f, 0.f, 0.f, 0.f};
#pragma unroll
  for (int mt = 0; mt < 4; ++mt)
#pragma unroll
    for (int nt = 0; nt < 2; ++nt) acc[mt][nt] = zero;
  int lr = l & 15, lg = l >> 4;
  int sc = (l & 7) * 8;
  for (int kt = 0; kt < nk; ++kt) {
    int ka = kA0 + kt * 64, kb = kt * 64;
#pragma unroll
    for (int c2 = 0; c2 < 4; ++c2)
      GLDS16(H + (size_t)(m0 + w * 32 + c2 * 8 + (l >> 3)) * 2048 + ka + sc,
             As + (w * 32 + c2 * 8) * 64);
#pragma unroll
    for (int c2 = 0; c2 < 2; ++c2)
      GLDS16(Bp + (size_t)(n0 + w * 16 + c2 * 8 + (l >> 3)) * brs + kb + sc,
             Bs + (w * 16 + c2 * 8) * 64);
    __syncthreads();
#pragma unroll
    for (int ks = 0; ks < 2; ++ks) {
      f16x8 af[4], bf[2];
#pragma unroll
      for (int mt = 0; mt < 4; ++mt)
        af[mt] = *(const f16x8*)&As[(wm + mt * 16 + lr) * 64 + ks * 32 + 8 * lg];
#pragma unroll
      for (int nt = 0; nt < 2; ++nt)
        bf[nt] = *(const f16x8*)&Bs[(wn + nt * 16 + lr) * 64 + ks * 32 + 8 * lg];
#pragma unroll
      for (int mt = 0; mt < 4; ++mt)
#pragma unroll
        for (int nt = 0; nt < 2; ++nt)
          acc[mt][nt] = __builtin_amdgcn_mfma_f32_16x16x32_f16(af[mt], bf[nt], acc[mt][nt], 0, 0, 0);
    }
    __syncthreads();
  }
}

__global__ __launch_bounds__(256) void k_fusion(
    const f16* __restrict__ H, const f16* __restrict__ Wg16,
    const f16* __restrict__ Wa16, const f16* __restrict__ Wm16,
    const float* __restrict__ bg, const float* __restrict__ ba,
    const float* __restrict__ bm, float* __restrict__ out) {
  __shared__ alignas(16) f16 As[128 * 64];
  __shared__ alignas(16) f16 Bs[64 * 64];
  int tid = threadIdx.x, l = tid & 63, w = tid >> 6;
  int m0 = blockIdx.x * 128, n0 = blockIdx.y * 64;
  int wm = (w & 1) * 64, wn = (w >> 1) * 32;
  int lr = l & 15, lg = l >> 4;

  f32x4 acc[4][2];
  float ta[4][2][4], tm[4][2][4];

  gemm_phase(H, 0, Wa16, 1024, 16, As, Bs, m0, n0, w, l, wm, wn, acc);
#pragma unroll
  for (int nt = 0; nt < 2; ++nt) {
    float bv = ba[n0 + wn + nt * 16 + lr];
#pragma unroll
    for (int mt = 0; mt < 4; ++mt)
#pragma unroll
      for (int r = 0; r < 4; ++r) ta[mt][nt][r] = tanh2(acc[mt][nt][r] + bv);
  }
  gemm_phase(H, 1024, Wm16, 1024, 16, As, Bs, m0, n0, w, l, wm, wn, acc);
#pragma unroll
  for (int nt = 0; nt < 2; ++nt) {
    float bv = bm[n0 + wn + nt * 16 + lr];
#pragma unroll
    for (int mt = 0; mt < 4; ++mt)
#pragma unroll
      for (int r = 0; r < 4; ++r) tm[mt][nt][r] = tanh2(acc[mt][nt][r] + bv);
  }
  gemm_phase(H, 0, Wg16, 2048, 32, As, Bs, m0, n0, w, l, wm, wn, acc);
#pragma unroll
  for (int nt = 0; nt < 2; ++nt) {
    int n = n0 + wn + nt * 16 + lr;
    float bv = bg[n];
#pragma unroll
    for (int mt = 0; mt < 4; ++mt) {
      int m = m0 + wm + mt * 16 + lg * 4;
#pragma unroll
      for (int r = 0; r < 4; ++r) {
        float g = sigf(acc[mt][nt][r] + bv);
        out[(size_t)(m + r) * 1024 + n] = tm[mt][nt][r] + g * (ta[mt][nt][r] - tm[mt][nt][r]);
      }
    }
  }
}

// ===========================================================================
extern "C" void kernel_launch(void* const* d_in, const int* in_sizes, int n_in,
                              void* d_out, int out_size, void* d_ws, size_t ws_size,
                              hipStream_t stream) {
  const float* xa = (const float*)d_in[0];
  const float* xm = (const float*)d_in[1];
  const float* Wih_1a = (const float*)d_in[2];
  const float* Whh_1a = (const float*)d_in[3];
  const float* bih_1a = (const float*)d_in[4];
  const float* bhh_1a = (const float*)d_in[5];
  const float* Wih_2a = (const float*)d_in[6];
  const float* Whh_2a = (const float*)d_in[7];
  const float* bih_2a = (const float*)d_in[8];
  const float* bhh_2a = (const float*)d_in[9];
  const float* Wih_1m = (const float*)d_in[10];
  const float* Whh_1m = (const float*)d_in[11];
  const float* bih_1m = (const float*)d_in[12];
  const float* bhh_1m = (const float*)d_in[13];
  const float* Wih_2m = (const float*)d_in[14];
  const float* Whh_2m = (const float*)d_in[15];
  const float* bih_2m = (const float*)d_in[16];
  const float* bhh_2m = (const float*)d_in[17];
  const float* Wg = (const float*)d_in[18];
  const float* bg = (const float*)d_in[19];
  const float* Wa = (const float*)d_in[20];
  const float* ba = (const float*)d_in[21];
  const float* Wm = (const float*)d_in[22];
  const float* bm = (const float*)d_in[23];

  char* ws = (char*)d_ws;
  const size_t MB = 1024ull * 1024;
  if (ws_size < 138 * MB) return;  // fail visibly

  f16* x16a    = (f16*)(ws + 0 * MB);     // dead after GEMM A
  f16* x16m    = (f16*)(ws + 8 * MB);     // dead after GEMM A
  f16* W1ih16a = (f16*)(ws + 16 * MB);    // dead after GEMM A
  f16* W1ih16m = (f16*)(ws + 32 * MB);    // dead after GEMM A
  f16* W1p_a   = (f16*)(ws + 48 * MB);
  f16* W1p_m   = (f16*)(ws + 56 * MB);
  f16* W2p_a   = (f16*)(ws + 64 * MB);
  f16* W2p_m   = (f16*)(ws + 80 * MB);
  f16* Wg16    = (f16*)(ws + 96 * MB);
  f16* Wa16    = (f16*)(ws + 100 * MB);
  f16* Wm16    = (f16*)(ws + 102 * MB);
  f16* G0a     = (f16*)(ws + 104 * MB);
  f16* G0m     = (f16*)(ws + 120 * MB);
  unsigned* flags1 = (unsigned*)(ws + 136 * MB);            // 32 KB
  unsigned* flags2 = (unsigned*)(ws + 136 * MB + 32768);    // 32 KB
  // aliases over GEMM-A-dead regions:
  f16* HaHm    = (f16*)(ws + 0 * MB);     // 8 MB over x16a
  f16* H1h     = (f16*)(ws + 8 * MB);     // 8 MB over x16m
  f16* h2c     = (f16*)(ws + 16 * MB);    // 8 MB over W1ih16a

  dim3 B256(256);
  k_cvt_all<<<28672, B256, 0, stream>>>(xa, x16a, xm, x16m, Wih_1a, W1ih16a,
                                        Wih_1m, W1ih16m, Wg, Wg16, Wa, Wa16,
                                        Wm, Wm16);
  k_packw1<<<dim3(2048, 2), B256, 0, stream>>>(Whh_1a, Whh_1m, W1p_a, W1p_m);
  k_packw2<<<dim3(4096, 2), B256, 0, stream>>>(Wih_2a, Whh_2a, Wih_2m, Whh_2m,
                                               W2p_a, W2p_m);
  hipMemsetAsync(flags1, 0, 65536, stream);   // flags1 + flags2

  // GEMM A: G0 = x @ Wih_1^T + (bih_1 + bhh_1)
  k_igemm<32, 2048><<<dim3(16, 32, 2), B256, 0, stream>>>(
      x16a, x16m, W1ih16a, W1ih16m, bih_1a, bhh_1a, bih_1m, bhh_1m, G0a, G0m);

  // dataflow scan (both cells, both streams)
  k_scan2<<<256, dim3(512), 0, stream>>>(
      W1p_a, W1p_m, W2p_a, W2p_m, G0a, G0m,
      bih_2a, bhh_2a, bih_2m, bhh_2m, H1h, h2c, HaHm, flags1, flags2);

  k_fusion<<<dim3(16, 16), B256, 0, stream>>>(HaHm, Wg16, Wa16, Wm16, bg, ba,
                                              bm, (float*)d_out);
}